// Round 3
// baseline (728.346 us; speedup 1.0000x reference)
//
#include <hip/hip_runtime.h>
#include <stdint.h>

#define LN_EPS 1e-5f

// ---------- bf16 helpers (RNE, bit-level) ----------
static __device__ __forceinline__ unsigned short f2bf_bits(float f) {
  union { float f; unsigned u; } v; v.f = f;
  unsigned r = v.u + 0x7FFFu + ((v.u >> 16) & 1u);
  return (unsigned short)(r >> 16);
}
static __device__ __forceinline__ float bf2f(unsigned short h) {
  union { unsigned u; float f; } v; v.u = ((unsigned)h) << 16;
  return v.f;
}

typedef __bf16 bf16x8 __attribute__((ext_vector_type(8)));
typedef float floatx4 __attribute__((ext_vector_type(4)));

// ---------- async global->LDS, 16B per lane ----------
typedef __attribute__((address_space(1))) unsigned int* gas_ptr;
typedef __attribute__((address_space(3))) unsigned int* las_ptr;
static __device__ __forceinline__ void async_cp16(const void* g, void* l) {
  __builtin_amdgcn_global_load_lds((gas_ptr)g, (las_ptr)l, 16, 0, 0);
}

// =====================================================================================
// K_a: fp32 -> bf16 weight conversion
// =====================================================================================
__global__ __launch_bounds__(256) void wconv_kernel(
    const float* __restrict__ w2, const float* __restrict__ w3,
    const float* __restrict__ w4, unsigned short* __restrict__ w2b,
    unsigned short* __restrict__ w3Rb, unsigned short* __restrict__ w4b) {
  int idx = blockIdx.x * 256 + threadIdx.x;   // 688128 total
  if (idx < 32768) {
    w2b[idx] = f2bf_bits(w2[idx]);
  } else if (idx < 32768 + 131072) {
    int t = idx - 32768;
    int p = t >> 8, k = t & 255;
    w3Rb[t] = f2bf_bits(w3[p * 512 + 256 + k]);   // w3[:, 256:512]
  } else {
    int t = idx - 163840;
    w4b[t] = f2bf_bits(w4[t]);
  }
}

// =====================================================================================
// K_b: conv1 (K=3, fp32 exact) + LayerNorm(128) + mask + relu -> h2 bf16 [131072 x 128]
// =====================================================================================
__global__ __launch_bounds__(256) void conv1_ln_kernel(
    const float* __restrict__ points, const int* __restrict__ mask,
    const float* __restrict__ w1, const float* __restrict__ g1,
    const float* __restrict__ be1, unsigned short* __restrict__ h2) {
  const int lane = threadIdx.x & 63;
  const int wv = threadIdx.x >> 6;
  const size_t p = (size_t)blockIdx.x * 4 + wv;
  const float x0 = points[p * 3 + 0];
  const float x1 = points[p * 3 + 1];
  const float x2 = points[p * 3 + 2];
  const int c0 = lane * 2, c1 = c0 + 1;
  float h00 = w1[c0 * 3] * x0 + w1[c0 * 3 + 1] * x1 + w1[c0 * 3 + 2] * x2;
  float h01 = w1[c1 * 3] * x0 + w1[c1 * 3 + 1] * x1 + w1[c1 * 3 + 2] * x2;
  float s = h00 + h01;
  for (int o = 32; o; o >>= 1) s += __shfl_xor(s, o);
  const float mu = s * (1.f / 128.f);
  const float d0 = h00 - mu, d1 = h01 - mu;
  float q = d0 * d0 + d1 * d1;
  for (int o = 32; o; o >>= 1) q += __shfl_xor(q, o);
  const float rs = rsqrtf(q * (1.f / 128.f) + LN_EPS);
  const bool vis = (mask[p] != 0);
  const float y0 = vis ? fmaxf(d0 * rs * g1[c0] + be1[c0], 0.f) : 0.f;
  const float y1 = vis ? fmaxf(d1 * rs * g1[c1] + be1[c1], 0.f) : 0.f;
  union { unsigned u; unsigned short s2[2]; } pk;
  pk.s2[0] = f2bf_bits(y0);
  pk.s2[1] = f2bf_bits(y1);
  ((unsigned*)h2)[p * 64 + lane] = pk.u;
}

// =====================================================================================
// MFMA GEMM: C[M,N] = A[M,K] * Bw[N,K]^T  (bf16 in, fp32 acc).
// Tile: 128 rows x 256 cols, BK=32. 4 waves in 2x2 (wave = 64 rows x 128 cols),
// acc[4][8] of 16x16x32 MFMA. Per iter: 32 MFMA, 12 ds_read_b128, 6 cp16.
// 1D grid swizzled (GROUP_ROWS row-tiles x NCT col-tiles, col fastest).
// EPI 0: out bf16 = acc + extra[col]                       (bias)
// EPI 1: out bf16 = acc + extra[(row>>12)*N + col]         (per-batch cvec)
// EPI 2: outp2[rowTile*N + colBase+t] = colmax over 128 rows (no store, no bias)
// EPI 3: EPI0 store + colmax(acc+bias) -> outp2
// =====================================================================================
template <int EPI, int NCT>
__global__ __launch_bounds__(256) void gemm_bt(
    const unsigned short* __restrict__ A, const unsigned short* __restrict__ Bw,
    void* __restrict__ outp, float* __restrict__ outp2,
    const float* __restrict__ extra, int M, int N, int K) {
  __shared__ __align__(16) char smA[128 * 64];   // 8 KB: 128 rows x 32 bf16
  __shared__ __align__(16) char smB[256 * 64];   // 16 KB: 256 "cols" x 32 bf16
  __shared__ float lmax[2][256];

  const int tid = threadIdx.x;
  const int lane = tid & 63;
  const int w = tid >> 6;          // wave 0..3
  const int wm = w >> 1, wn = w & 1;   // wm: row half (64), wn: col half (128)

  const int GROUP_ROWS = 64;
  const int perGroup = GROUP_ROWS * NCT;
  const int gid = blockIdx.x;
  const int group = gid / perGroup;
  const int within = gid - group * perGroup;
  const int rowTile = group * GROUP_ROWS + (within / NCT);
  const int colTile = within % NCT;
  const size_t rowBase = (size_t)rowTile * 128;
  const int colBase = colTile * 256;

  floatx4 acc[4][8];
  const floatx4 zero = {0.f, 0.f, 0.f, 0.f};
#pragma unroll
  for (int i = 0; i < 4; ++i)
#pragma unroll
    for (int j = 0; j < 8; ++j) acc[i][j] = zero;

  // staging: wave w stages A rows [w*32, w*32+32) (2 calls) and B rows [w*64, w*64+64) (4 calls)
  const int rSub = lane >> 2;            // 0..15
  const int cb16 = (lane & 3) * 16;
  const size_t Kb = (size_t)K * 2;
  const char* gA = (const char*)A + (rowBase + (size_t)(w * 32 + rSub)) * Kb + cb16;
  const char* gB = (const char*)Bw + ((size_t)colBase + (size_t)(w * 64 + rSub)) * Kb + cb16;
  char* lA = smA + w * 2048;
  char* lB = smB + w * 4096;
  const size_t skip16 = 16 * Kb;

  // fragment addressing
  const int fm = lane & 15, fq = lane >> 4;
  const char* pa0 = smA + (wm * 64 + fm) * 64 + fq * 16;
  const char* pb0 = smB + (wn * 128 + fm) * 64 + fq * 16;

  for (int k0 = 0; k0 < K; k0 += 32) {
    async_cp16(gA, lA);
    async_cp16(gA + skip16, lA + 1024);
    async_cp16(gB, lB);
    async_cp16(gB + skip16, lB + 1024);
    async_cp16(gB + 2 * skip16, lB + 2048);
    async_cp16(gB + 3 * skip16, lB + 3072);
    gA += 64; gB += 64;
    __syncthreads();
    bf16x8 af[4], bg[8];
#pragma unroll
    for (int i = 0; i < 4; ++i) af[i] = *(const bf16x8*)(pa0 + i * 16 * 64);
#pragma unroll
    for (int j = 0; j < 8; ++j) bg[j] = *(const bf16x8*)(pb0 + j * 16 * 64);
#pragma unroll
    for (int i = 0; i < 4; ++i)
#pragma unroll
      for (int j = 0; j < 8; ++j)
        acc[i][j] = __builtin_amdgcn_mfma_f32_16x16x32_bf16(af[i], bg[j], acc[i][j], 0, 0, 0);
    __syncthreads();
  }

  float m8[8] = {-1e30f, -1e30f, -1e30f, -1e30f, -1e30f, -1e30f, -1e30f, -1e30f};

  if (EPI == 0 || EPI == 1 || EPI == 3) {
    unsigned short* O = (unsigned short*)outp;
#pragma unroll
    for (int j = 0; j < 8; ++j) {
      const int col = colBase + wn * 128 + j * 16 + fm;
      const float ex = (EPI == 1) ? extra[(rowBase >> 12) * (size_t)N + col] : extra[col];
#pragma unroll
      for (int i = 0; i < 4; ++i) {
        const size_t row0 = rowBase + wm * 64 + i * 16 + fq * 4;
#pragma unroll
        for (int r = 0; r < 4; ++r) {
          const float v = acc[i][j][r] + ex;
          if (EPI == 3) m8[j] = fmaxf(m8[j], v);
          O[(row0 + r) * (size_t)N + col] = f2bf_bits(v);
        }
      }
    }
  } else {  // EPI == 2: pure column-max
#pragma unroll
    for (int j = 0; j < 8; ++j) {
#pragma unroll
      for (int i = 0; i < 4; ++i)
#pragma unroll
        for (int r = 0; r < 4; ++r) m8[j] = fmaxf(m8[j], acc[i][j][r]);
    }
  }

  if (EPI == 2 || EPI == 3) {
#pragma unroll
    for (int j = 0; j < 8; ++j) {
      m8[j] = fmaxf(m8[j], __shfl_xor(m8[j], 16));
      m8[j] = fmaxf(m8[j], __shfl_xor(m8[j], 32));
    }
    // lane (fq, fm) owns cols j=fq and j=fq+4 within this wave's 128-col half
    const float sel0 = (fq == 0) ? m8[0] : (fq == 1) ? m8[1] : (fq == 2) ? m8[2] : m8[3];
    const float sel1 = (fq == 0) ? m8[4] : (fq == 1) ? m8[5] : (fq == 2) ? m8[6] : m8[7];
    lmax[wm][wn * 128 + fq * 16 + fm] = sel0;
    lmax[wm][wn * 128 + 64 + fq * 16 + fm] = sel1;
    __syncthreads();
    const float v = fmaxf(lmax[0][tid], lmax[1][tid]);
    outp2[(size_t)rowTile * N + colBase + tid] = v;
  }
}

// =====================================================================================
// gmax reduce: pg [B,32,256] (per-128-row-block colmax from GEMM2 epi) -> gmax [B,256]
// =====================================================================================
__global__ __launch_bounds__(256) void gmax_red_kernel(
    const float* __restrict__ pg, float* __restrict__ gmax) {
  const int b = blockIdx.x, t = threadIdx.x;
  float m = -1e30f;
  for (int s = 0; s < 32; ++s) m = fmaxf(m, pg[((size_t)b * 32 + s) * 256 + t]);
  gmax[b * 256 + t] = m;
}

// =====================================================================================
// cvec[b][p] = sum_{c<256} w3[p][c] * gmax[b][c]   (fp32 exact, tiny)
// =====================================================================================
__global__ __launch_bounds__(64) void cvec_kernel(
    const float* __restrict__ w3, const float* __restrict__ gmax,
    float* __restrict__ cvec) {
  __shared__ float gm[256];
  const int b = blockIdx.x, t = threadIdx.x;
  const int p = blockIdx.y * 64 + t;
  for (int i = 0; i < 4; ++i) gm[t * 4 + i] = gmax[b * 256 + t * 4 + i];
  __syncthreads();
  const float* wr = w3 + (size_t)p * 512;
  float s = 0.f;
  for (int c = 0; c < 256; ++c) s += wr[c] * gm[c];
  cvec[b * 512 + p] = s;
}

// =====================================================================================
// K_h: LayerNorm(512) + mask + relu, in place on h46 bf16 [131072 x 512]
// =====================================================================================
__global__ __launch_bounds__(256) void ln2_kernel(
    unsigned short* __restrict__ h46, const int* __restrict__ mask,
    const float* __restrict__ g2, const float* __restrict__ be2) {
  const int lane = threadIdx.x & 63;
  const int wv = threadIdx.x >> 6;
  const size_t p = (size_t)blockIdx.x * 4 + wv;
  unsigned short* row = h46 + p * 512;
  const int c0 = lane * 8;
  union { uint4 v; unsigned short s[8]; } in;
  in.v = *(const uint4*)(row + c0);
  float f[8];
  float s = 0.f;
#pragma unroll
  for (int k = 0; k < 8; ++k) { f[k] = bf2f(in.s[k]); s += f[k]; }
  for (int o = 32; o; o >>= 1) s += __shfl_xor(s, o);
  const float mu = s * (1.f / 512.f);
  float q = 0.f;
#pragma unroll
  for (int k = 0; k < 8; ++k) { const float d = f[k] - mu; q += d * d; }
  for (int o = 32; o; o >>= 1) q += __shfl_xor(q, o);
  const float rs = rsqrtf(q * (1.f / 512.f) + LN_EPS);
  const bool vis = (mask[p] != 0);
  union { uint4 v; unsigned short s[8]; } outv;
#pragma unroll
  for (int k = 0; k < 8; ++k) {
    const float y = vis ? fmaxf((f[k] - mu) * rs * g2[c0 + k] + be2[c0 + k], 0.f) : 0.f;
    outv.s[k] = f2bf_bits(y);
  }
  *(uint4*)(row + c0) = outv.v;
}

// =====================================================================================
// K_j: out[b][f] = max over 32 row-blocks of pmax + b4[f]
// =====================================================================================
__global__ __launch_bounds__(256) void final_kernel(
    const float* __restrict__ pmax, const float* __restrict__ b4,
    float* __restrict__ out) {
  const int idx = blockIdx.x * 256 + threadIdx.x;
  const int b = idx >> 10, f = idx & 1023;
  float m = -1e30f;
  for (int r = 0; r < 32; ++r) m = fmaxf(m, pmax[((size_t)(b * 32 + r)) * 1024 + f]);
  out[idx] = m + b4[f];
}

// =====================================================================================
extern "C" void kernel_launch(void* const* d_in, const int* in_sizes, int n_in,
                              void* d_out, int out_size, void* d_ws, size_t ws_size,
                              hipStream_t stream) {
  const float* points = (const float*)d_in[0];
  const int* mask = (const int*)d_in[1];
  const float* w1 = (const float*)d_in[2];
  const float* g1 = (const float*)d_in[3];
  const float* be1 = (const float*)d_in[4];
  const float* w2 = (const float*)d_in[5];
  const float* b2 = (const float*)d_in[6];
  const float* w3 = (const float*)d_in[7];
  const float* g2 = (const float*)d_in[8];
  const float* be2 = (const float*)d_in[9];
  const float* w4 = (const float*)d_in[10];
  const float* b4 = (const float*)d_in[11];
  float* out = (float*)d_out;
  char* ws = (char*)d_ws;

  // workspace layout (h46 aliases h2: h2 is dead before GEMM3 writes h46)
  const size_t OFF_H46 = 0;                         // 134217728 B (bf16 131072x512)
  const size_t OFF_H2 = 0;                          //  33554432 B (bf16 131072x128)
  const size_t OFF_H3 = 134217728;                  //  67108864 B (bf16 131072x256)
  const size_t OFF_W2B = OFF_H3 + 67108864;         //     65536 B
  const size_t OFF_W3RB = OFF_W2B + 65536;          //    262144 B
  const size_t OFF_W4B = OFF_W3RB + 262144;         //   1048576 B
  const size_t OFF_PG = OFF_W4B + 1048576;          //   1048576 B (pg: 1024x256 f32)
  const size_t OFF_GMAX = OFF_PG + 1048576;         //     32768 B
  const size_t OFF_CVEC = OFF_GMAX + 32768;         //     65536 B
  const size_t OFF_PMAX = OFF_CVEC + 65536;         //   4194304 B

  unsigned short* h2 = (unsigned short*)(ws + OFF_H2);
  unsigned short* h3 = (unsigned short*)(ws + OFF_H3);
  unsigned short* h46 = (unsigned short*)(ws + OFF_H46);
  unsigned short* w2b = (unsigned short*)(ws + OFF_W2B);
  unsigned short* w3Rb = (unsigned short*)(ws + OFF_W3RB);
  unsigned short* w4b = (unsigned short*)(ws + OFF_W4B);
  float* pg = (float*)(ws + OFF_PG);
  float* gmaxp = (float*)(ws + OFF_GMAX);
  float* cvecp = (float*)(ws + OFF_CVEC);
  float* pmaxp = (float*)(ws + OFF_PMAX);

  // 1. weights fp32->bf16
  wconv_kernel<<<2688, 256, 0, stream>>>(w2, w3, w4, w2b, w3Rb, w4b);
  // 2. conv1 + LN1 + mask + relu -> h2
  conv1_ln_kernel<<<32768, 256, 0, stream>>>(points, mask, w1, g1, be1, h2);
  // 3. h3 = h2 @ w2^T + b2, fused per-row-block colmax -> pg  (full N in one block)
  gemm_bt<3, 1><<<1024, 256, 0, stream>>>(h2, w2b, (void*)h3, pg, b2, 131072, 256, 128);
  // 4. gmax = max over row-blocks of pg
  gmax_red_kernel<<<32, 256, 0, stream>>>(pg, gmaxp);
  // 5. cvec = w3[:, :256] @ gmax
  cvec_kernel<<<dim3(32, 8), 64, 0, stream>>>(w3, gmaxp, cvecp);
  // 6. h4 = h3 @ w3[:,256:]^T + cvec[b]
  gemm_bt<1, 2><<<2048, 256, 0, stream>>>(h3, w3Rb, (void*)h46, nullptr, cvecp, 131072, 512, 256);
  // 7. LN2 + mask + relu in place
  ln2_kernel<<<32768, 256, 0, stream>>>(h46, mask, g2, be2);
  // 8. h7 colmax: fused per-row-block column-max -> pmax (bias deferred)
  gemm_bt<2, 4><<<4096, 256, 0, stream>>>(h46, w4b, nullptr, pmaxp, nullptr, 131072, 1024, 512);
  // 9. out = max over row-blocks + b4
  final_kernel<<<128, 256, 0, stream>>>(pmaxp, b4, out);
}

// Round 4
// 497.485 us; speedup vs baseline: 1.4641x; 1.4641x over previous
//
#include <hip/hip_runtime.h>
#include <stdint.h>

#define LN_EPS 1e-5f

// ---------- bf16 helpers (RNE, bit-level) ----------
static __device__ __forceinline__ unsigned short f2bf_bits(float f) {
  union { float f; unsigned u; } v; v.f = f;
  unsigned r = v.u + 0x7FFFu + ((v.u >> 16) & 1u);
  return (unsigned short)(r >> 16);
}
static __device__ __forceinline__ float bf2f(unsigned short h) {
  union { unsigned u; float f; } v; v.u = ((unsigned)h) << 16;
  return v.f;
}

typedef __bf16 bf16x8 __attribute__((ext_vector_type(8)));
typedef float floatx4 __attribute__((ext_vector_type(4)));

// ---------- async global->LDS, 16B per lane ----------
typedef __attribute__((address_space(1))) unsigned int* gas_ptr;
typedef __attribute__((address_space(3))) unsigned int* las_ptr;
static __device__ __forceinline__ void async_cp16(const void* g, void* l) {
  __builtin_amdgcn_global_load_lds((gas_ptr)g, (las_ptr)l, 16, 0, 0);
}

// =====================================================================================
// K_a: fp32 -> bf16 weight conversion
// =====================================================================================
__global__ __launch_bounds__(256) void wconv_kernel(
    const float* __restrict__ w2, const float* __restrict__ w3,
    const float* __restrict__ w4, unsigned short* __restrict__ w2b,
    unsigned short* __restrict__ w3Rb, unsigned short* __restrict__ w4b) {
  int idx = blockIdx.x * 256 + threadIdx.x;   // 688128 total
  if (idx < 32768) {
    w2b[idx] = f2bf_bits(w2[idx]);
  } else if (idx < 32768 + 131072) {
    int t = idx - 32768;
    int p = t >> 8, k = t & 255;
    w3Rb[t] = f2bf_bits(w3[p * 512 + 256 + k]);   // w3[:, 256:512]
  } else {
    int t = idx - 163840;
    w4b[t] = f2bf_bits(w4[t]);
  }
}

// =====================================================================================
// K_b: conv1 (K=3, fp32 exact) + LayerNorm(128) + mask + relu -> h2 bf16 [131072 x 128]
// =====================================================================================
__global__ __launch_bounds__(256) void conv1_ln_kernel(
    const float* __restrict__ points, const int* __restrict__ mask,
    const float* __restrict__ w1, const float* __restrict__ g1,
    const float* __restrict__ be1, unsigned short* __restrict__ h2) {
  const int lane = threadIdx.x & 63;
  const int wv = threadIdx.x >> 6;
  const size_t p = (size_t)blockIdx.x * 4 + wv;
  const float x0 = points[p * 3 + 0];
  const float x1 = points[p * 3 + 1];
  const float x2 = points[p * 3 + 2];
  const int c0 = lane * 2, c1 = c0 + 1;
  float h00 = w1[c0 * 3] * x0 + w1[c0 * 3 + 1] * x1 + w1[c0 * 3 + 2] * x2;
  float h01 = w1[c1 * 3] * x0 + w1[c1 * 3 + 1] * x1 + w1[c1 * 3 + 2] * x2;
  float s = h00 + h01;
  for (int o = 32; o; o >>= 1) s += __shfl_xor(s, o);
  const float mu = s * (1.f / 128.f);
  const float d0 = h00 - mu, d1 = h01 - mu;
  float q = d0 * d0 + d1 * d1;
  for (int o = 32; o; o >>= 1) q += __shfl_xor(q, o);
  const float rs = rsqrtf(q * (1.f / 128.f) + LN_EPS);
  const bool vis = (mask[p] != 0);
  const float y0 = vis ? fmaxf(d0 * rs * g1[c0] + be1[c0], 0.f) : 0.f;
  const float y1 = vis ? fmaxf(d1 * rs * g1[c1] + be1[c1], 0.f) : 0.f;
  union { unsigned u; unsigned short s2[2]; } pk;
  pk.s2[0] = f2bf_bits(y0);
  pk.s2[1] = f2bf_bits(y1);
  ((unsigned*)h2)[p * 64 + lane] = pk.u;
}

// =====================================================================================
// MFMA GEMM: C[M,N] = A[M,K] * Bw[N,K]^T  (bf16 in, fp32 acc), 128x128 tile (m97).
// XCD-aware swizzle: xcd = gid & 7 (round-robin dispatch), each XCD owns a
// contiguous band of row-tiles, col-tile fastest within the band -> the NCT
// blocks sharing one A row-tile are co-resident on ONE XCD's private L2.
// EPI 0: out bf16 = acc + extra[col]                       (bias)
// EPI 1: out bf16 = acc + extra[(row>>12)*N + col]         (per-batch cvec)
// EPI 2: outp2[rowTile*N + col] = colmax over 128 rows     (no store, no bias)
// EPI 3: EPI0 store + colmax(acc+bias) -> outp2
// =====================================================================================
template <int EPI, int NCT>
__global__ __launch_bounds__(256) void gemm_bt(
    const unsigned short* __restrict__ A, const unsigned short* __restrict__ Bw,
    void* __restrict__ outp, float* __restrict__ outp2,
    const float* __restrict__ extra, int M, int N, int K) {
  __shared__ __align__(16) char smA[128 * 64];   // 128 rows x 32 bf16 (64B), unpadded
  __shared__ __align__(16) char smB[128 * 64];
  __shared__ float lmax[2][128];

  const int tid = threadIdx.x;
  const int lane = tid & 63;
  const int w = tid >> 6;          // wave 0..3
  const int wm = w >> 1, wn = w & 1;

  // XCD-aware tile coordinates
  const int gid = blockIdx.x;
  const int xcd = gid & 7;
  const int slot = gid >> 3;
  const int rowsPerXcd = (M >> 7) >> 3;          // NRT / 8
  const int rowTile = xcd * rowsPerXcd + slot / NCT;
  const int colTile = slot % NCT;
  const size_t rowBase = (size_t)rowTile * 128;
  const int colBase = colTile * 128;

  floatx4 acc[4][4];
  const floatx4 zero = {0.f, 0.f, 0.f, 0.f};
#pragma unroll
  for (int i = 0; i < 4; ++i)
#pragma unroll
    for (int j = 0; j < 4; ++j) acc[i][j] = zero;

  // staging: wave w stages rows [w*32, w*32+32) of both tiles, 2 calls each
  const int rSub = lane >> 2;
  const int cb16 = (lane & 3) * 16;
  const size_t Kb = (size_t)K * 2;
  const char* gA = (const char*)A + (rowBase + (size_t)(w * 32 + rSub)) * Kb + cb16;
  const char* gB = (const char*)Bw + ((size_t)colBase + (size_t)(w * 32 + rSub)) * Kb + cb16;
  char* lA = smA + w * 2048;
  char* lB = smB + w * 2048;
  const size_t skip16 = 16 * Kb;

  // fragment addressing
  const int fm = lane & 15, fq = lane >> 4;
  const char* pa0 = smA + (wm * 64 + fm) * 64 + fq * 16;
  const char* pb0 = smB + (wn * 64 + fm) * 64 + fq * 16;

  for (int k0 = 0; k0 < K; k0 += 32) {
    async_cp16(gA, lA);
    async_cp16(gA + skip16, lA + 1024);
    async_cp16(gB, lB);
    async_cp16(gB + skip16, lB + 1024);
    gA += 64; gB += 64;
    __syncthreads();
    bf16x8 af[4], bg[4];
#pragma unroll
    for (int i = 0; i < 4; ++i) af[i] = *(const bf16x8*)(pa0 + i * 16 * 64);
#pragma unroll
    for (int j = 0; j < 4; ++j) bg[j] = *(const bf16x8*)(pb0 + j * 16 * 64);
#pragma unroll
    for (int i = 0; i < 4; ++i)
#pragma unroll
      for (int j = 0; j < 4; ++j)
        acc[i][j] = __builtin_amdgcn_mfma_f32_16x16x32_bf16(af[i], bg[j], acc[i][j], 0, 0, 0);
    __syncthreads();
  }

  float m4[4] = {-1e30f, -1e30f, -1e30f, -1e30f};

  if (EPI == 0 || EPI == 1 || EPI == 3) {
    unsigned short* O = (unsigned short*)outp;
#pragma unroll
    for (int j = 0; j < 4; ++j) {
      const int col = colBase + wn * 64 + j * 16 + fm;
      const float ex = (EPI == 1) ? extra[(rowBase >> 12) * (size_t)N + col] : extra[col];
#pragma unroll
      for (int i = 0; i < 4; ++i) {
        const size_t row0 = rowBase + wm * 64 + i * 16 + fq * 4;
#pragma unroll
        for (int r = 0; r < 4; ++r) {
          const float v = acc[i][j][r] + ex;
          if (EPI == 3) m4[j] = fmaxf(m4[j], v);
          O[(row0 + r) * (size_t)N + col] = f2bf_bits(v);
        }
      }
    }
  } else {  // EPI == 2: pure column-max
#pragma unroll
    for (int j = 0; j < 4; ++j) {
#pragma unroll
      for (int i = 0; i < 4; ++i)
#pragma unroll
        for (int r = 0; r < 4; ++r) m4[j] = fmaxf(m4[j], acc[i][j][r]);
    }
  }

  if (EPI == 2 || EPI == 3) {
#pragma unroll
    for (int j = 0; j < 4; ++j) {
      m4[j] = fmaxf(m4[j], __shfl_xor(m4[j], 16));
      m4[j] = fmaxf(m4[j], __shfl_xor(m4[j], 32));
    }
    const float sel = (fq == 0) ? m4[0] : (fq == 1) ? m4[1] : (fq == 2) ? m4[2] : m4[3];
    lmax[wm][wn * 64 + fq * 16 + fm] = sel;
    __syncthreads();
    if (tid < 128) {
      const float v = fmaxf(lmax[0][tid], lmax[1][tid]);
      outp2[(size_t)rowTile * N + colBase + tid] = v;
    }
  }
}

// =====================================================================================
// gmax reduce: pg [B,32,256] (per-128-row-block colmax from GEMM2 epi) -> gmax [B,256]
// =====================================================================================
__global__ __launch_bounds__(256) void gmax_red_kernel(
    const float* __restrict__ pg, float* __restrict__ gmax) {
  const int b = blockIdx.x, t = threadIdx.x;
  float m = -1e30f;
  for (int s = 0; s < 32; ++s) m = fmaxf(m, pg[((size_t)b * 32 + s) * 256 + t]);
  gmax[b * 256 + t] = m;
}

// =====================================================================================
// cvec[b][p] = sum_{c<256} w3[p][c] * gmax[b][c]   (fp32 exact, tiny)
// =====================================================================================
__global__ __launch_bounds__(64) void cvec_kernel(
    const float* __restrict__ w3, const float* __restrict__ gmax,
    float* __restrict__ cvec) {
  __shared__ float gm[256];
  const int b = blockIdx.x, t = threadIdx.x;
  const int p = blockIdx.y * 64 + t;
  for (int i = 0; i < 4; ++i) gm[t * 4 + i] = gmax[b * 256 + t * 4 + i];
  __syncthreads();
  const float* wr = w3 + (size_t)p * 512;
  float s = 0.f;
  for (int c = 0; c < 256; ++c) s += wr[c] * gm[c];
  cvec[b * 512 + p] = s;
}

// =====================================================================================
// K_h: LayerNorm(512) + mask + relu, in place on h46 bf16 [131072 x 512]
// =====================================================================================
__global__ __launch_bounds__(256) void ln2_kernel(
    unsigned short* __restrict__ h46, const int* __restrict__ mask,
    const float* __restrict__ g2, const float* __restrict__ be2) {
  const int lane = threadIdx.x & 63;
  const int wv = threadIdx.x >> 6;
  const size_t p = (size_t)blockIdx.x * 4 + wv;
  unsigned short* row = h46 + p * 512;
  const int c0 = lane * 8;
  union { uint4 v; unsigned short s[8]; } in;
  in.v = *(const uint4*)(row + c0);
  float f[8];
  float s = 0.f;
#pragma unroll
  for (int k = 0; k < 8; ++k) { f[k] = bf2f(in.s[k]); s += f[k]; }
  for (int o = 32; o; o >>= 1) s += __shfl_xor(s, o);
  const float mu = s * (1.f / 512.f);
  float q = 0.f;
#pragma unroll
  for (int k = 0; k < 8; ++k) { const float d = f[k] - mu; q += d * d; }
  for (int o = 32; o; o >>= 1) q += __shfl_xor(q, o);
  const float rs = rsqrtf(q * (1.f / 512.f) + LN_EPS);
  const bool vis = (mask[p] != 0);
  union { uint4 v; unsigned short s[8]; } outv;
#pragma unroll
  for (int k = 0; k < 8; ++k) {
    const float y = vis ? fmaxf((f[k] - mu) * rs * g2[c0 + k] + be2[c0 + k], 0.f) : 0.f;
    outv.s[k] = f2bf_bits(y);
  }
  *(uint4*)(row + c0) = outv.v;
}

// =====================================================================================
// K_j: out[b][f] = max over 32 row-blocks of pmax + b4[f]
// =====================================================================================
__global__ __launch_bounds__(256) void final_kernel(
    const float* __restrict__ pmax, const float* __restrict__ b4,
    float* __restrict__ out) {
  const int idx = blockIdx.x * 256 + threadIdx.x;
  const int b = idx >> 10, f = idx & 1023;
  float m = -1e30f;
  for (int r = 0; r < 32; ++r) m = fmaxf(m, pmax[((size_t)(b * 32 + r)) * 1024 + f]);
  out[idx] = m + b4[f];
}

// =====================================================================================
extern "C" void kernel_launch(void* const* d_in, const int* in_sizes, int n_in,
                              void* d_out, int out_size, void* d_ws, size_t ws_size,
                              hipStream_t stream) {
  const float* points = (const float*)d_in[0];
  const int* mask = (const int*)d_in[1];
  const float* w1 = (const float*)d_in[2];
  const float* g1 = (const float*)d_in[3];
  const float* be1 = (const float*)d_in[4];
  const float* w2 = (const float*)d_in[5];
  const float* b2 = (const float*)d_in[6];
  const float* w3 = (const float*)d_in[7];
  const float* g2 = (const float*)d_in[8];
  const float* be2 = (const float*)d_in[9];
  const float* w4 = (const float*)d_in[10];
  const float* b4 = (const float*)d_in[11];
  float* out = (float*)d_out;
  char* ws = (char*)d_ws;

  // workspace layout (h46 aliases h2: h2 is dead before GEMM3 writes h46)
  const size_t OFF_H46 = 0;                         // 134217728 B (bf16 131072x512)
  const size_t OFF_H2 = 0;                          //  33554432 B (bf16 131072x128)
  const size_t OFF_H3 = 134217728;                  //  67108864 B (bf16 131072x256)
  const size_t OFF_W2B = OFF_H3 + 67108864;         //     65536 B
  const size_t OFF_W3RB = OFF_W2B + 65536;          //    262144 B
  const size_t OFF_W4B = OFF_W3RB + 262144;         //   1048576 B
  const size_t OFF_PG = OFF_W4B + 1048576;          //   1048576 B (pg: 1024x256 f32)
  const size_t OFF_GMAX = OFF_PG + 1048576;         //     32768 B
  const size_t OFF_CVEC = OFF_GMAX + 32768;         //     65536 B
  const size_t OFF_PMAX = OFF_CVEC + 65536;         //   4194304 B

  unsigned short* h2 = (unsigned short*)(ws + OFF_H2);
  unsigned short* h3 = (unsigned short*)(ws + OFF_H3);
  unsigned short* h46 = (unsigned short*)(ws + OFF_H46);
  unsigned short* w2b = (unsigned short*)(ws + OFF_W2B);
  unsigned short* w3Rb = (unsigned short*)(ws + OFF_W3RB);
  unsigned short* w4b = (unsigned short*)(ws + OFF_W4B);
  float* pg = (float*)(ws + OFF_PG);
  float* gmaxp = (float*)(ws + OFF_GMAX);
  float* cvecp = (float*)(ws + OFF_CVEC);
  float* pmaxp = (float*)(ws + OFF_PMAX);

  // 1. weights fp32->bf16
  wconv_kernel<<<2688, 256, 0, stream>>>(w2, w3, w4, w2b, w3Rb, w4b);
  // 2. conv1 + LN1 + mask + relu -> h2
  conv1_ln_kernel<<<32768, 256, 0, stream>>>(points, mask, w1, g1, be1, h2);
  // 3. h3 = h2 @ w2^T + b2, fused per-row-block colmax -> pg
  gemm_bt<3, 2><<<2048, 256, 0, stream>>>(h2, w2b, (void*)h3, pg, b2, 131072, 256, 128);
  // 4. gmax = max over row-blocks of pg
  gmax_red_kernel<<<32, 256, 0, stream>>>(pg, gmaxp);
  // 5. cvec = w3[:, :256] @ gmax
  cvec_kernel<<<dim3(32, 8), 64, 0, stream>>>(w3, gmaxp, cvecp);
  // 6. h4 = h3 @ w3[:,256:]^T + cvec[b]
  gemm_bt<1, 4><<<4096, 256, 0, stream>>>(h3, w3Rb, (void*)h46, nullptr, cvecp, 131072, 512, 256);
  // 7. LN2 + mask + relu in place
  ln2_kernel<<<32768, 256, 0, stream>>>(h46, mask, g2, be2);
  // 8. h7 colmax: fused per-row-block column-max -> pmax (bias deferred)
  gemm_bt<2, 8><<<8192, 256, 0, stream>>>(h46, w4b, nullptr, pmaxp, nullptr, 131072, 1024, 512);
  // 9. out = max over row-blocks + b4
  final_kernel<<<128, 256, 0, stream>>>(pmaxp, b4, out);
}

// Round 5
// 466.125 us; speedup vs baseline: 1.5626x; 1.0673x over previous
//
#include <hip/hip_runtime.h>
#include <stdint.h>

#define LN_EPS 1e-5f

// ---------- bf16 helpers (RNE, bit-level) ----------
static __device__ __forceinline__ unsigned short f2bf_bits(float f) {
  union { float f; unsigned u; } v; v.f = f;
  unsigned r = v.u + 0x7FFFu + ((v.u >> 16) & 1u);
  return (unsigned short)(r >> 16);
}
static __device__ __forceinline__ float bf2f(unsigned short h) {
  union { unsigned u; float f; } v; v.u = ((unsigned)h) << 16;
  return v.f;
}

typedef __bf16 bf16x8 __attribute__((ext_vector_type(8)));
typedef float floatx4 __attribute__((ext_vector_type(4)));

// ---------- async global->LDS, 16B per lane ----------
typedef __attribute__((address_space(1))) unsigned int* gas_ptr;
typedef __attribute__((address_space(3))) unsigned int* las_ptr;
static __device__ __forceinline__ void async_cp16(const void* g, void* l) {
  __builtin_amdgcn_global_load_lds((gas_ptr)g, (las_ptr)l, 16, 0, 0);
}

// =====================================================================================
// K_b: conv1 (K=3, fp32 exact) + LayerNorm(128) + mask + relu -> h2 bf16 [131072 x 128]
// blocks >= 32768 instead perform fp32->bf16 weight conversion (fused wconv).
// =====================================================================================
__global__ __launch_bounds__(256) void conv1_ln_kernel(
    const float* __restrict__ points, const int* __restrict__ mask,
    const float* __restrict__ w1, const float* __restrict__ g1,
    const float* __restrict__ be1, unsigned short* __restrict__ h2,
    const float* __restrict__ w2, const float* __restrict__ w3,
    const float* __restrict__ w4, unsigned short* __restrict__ w2b,
    unsigned short* __restrict__ w3Rb, unsigned short* __restrict__ w4b) {
  if (blockIdx.x >= 32768) {   // fused weight conversion: 2688 blocks, 688128 elems
    int idx = (blockIdx.x - 32768) * 256 + threadIdx.x;
    if (idx < 32768) {
      w2b[idx] = f2bf_bits(w2[idx]);
    } else if (idx < 32768 + 131072) {
      int t = idx - 32768;
      int p = t >> 8, k = t & 255;
      w3Rb[t] = f2bf_bits(w3[p * 512 + 256 + k]);   // w3[:, 256:512]
    } else {
      int t = idx - 163840;
      w4b[t] = f2bf_bits(w4[t]);
    }
    return;
  }
  const int lane = threadIdx.x & 63;
  const int wv = threadIdx.x >> 6;
  const size_t p = (size_t)blockIdx.x * 4 + wv;
  const float x0 = points[p * 3 + 0];
  const float x1 = points[p * 3 + 1];
  const float x2 = points[p * 3 + 2];
  const int c0 = lane * 2, c1 = c0 + 1;
  float h00 = w1[c0 * 3] * x0 + w1[c0 * 3 + 1] * x1 + w1[c0 * 3 + 2] * x2;
  float h01 = w1[c1 * 3] * x0 + w1[c1 * 3 + 1] * x1 + w1[c1 * 3 + 2] * x2;
  float s = h00 + h01;
  for (int o = 32; o; o >>= 1) s += __shfl_xor(s, o);
  const float mu = s * (1.f / 128.f);
  const float d0 = h00 - mu, d1 = h01 - mu;
  float q = d0 * d0 + d1 * d1;
  for (int o = 32; o; o >>= 1) q += __shfl_xor(q, o);
  const float rs = rsqrtf(q * (1.f / 128.f) + LN_EPS);
  const bool vis = (mask[p] != 0);
  const float y0 = vis ? fmaxf(d0 * rs * g1[c0] + be1[c0], 0.f) : 0.f;
  const float y1 = vis ? fmaxf(d1 * rs * g1[c1] + be1[c1], 0.f) : 0.f;
  union { unsigned u; unsigned short s2[2]; } pk;
  pk.s2[0] = f2bf_bits(y0);
  pk.s2[1] = f2bf_bits(y1);
  ((unsigned*)h2)[p * 64 + lane] = pk.u;
}

// =====================================================================================
// MFMA GEMM: C[M,N] = A[M,K] * Bw[N,K]^T  (bf16 in, fp32 acc), 128x128 tile.
// BK=64 as TWO 32-col panels (64B LDS rows preserved: conflict-free + legal
// global_load_lds lane mapping) -> half the barrier drains per FLOP vs BK=32.
// XCD-aware swizzle: xcd = gid & 7; each XCD owns a contiguous band of row-tiles,
// col-tile fastest, so blocks sharing an A row-tile sit on ONE XCD's L2.
// EPI 0: out bf16 = acc + extra[col]                       (bias)
// EPI 1: out bf16 = acc + extra[(row>>12)*N + col]         (per-batch cvec)
// EPI 2: outp2[rowTile*N + col] = colmax over 128 rows     (no store, no bias)
// EPI 3: EPI0 store + colmax(acc+bias) -> outp2
// =====================================================================================
template <int EPI, int NCT>
__global__ __launch_bounds__(256) void gemm_bt(
    const unsigned short* __restrict__ A, const unsigned short* __restrict__ Bw,
    void* __restrict__ outp, float* __restrict__ outp2,
    const float* __restrict__ extra, int M, int N, int K) {
  __shared__ __align__(16) char smA[2][128 * 64];   // two 8 KB panels (k lo/hi)
  __shared__ __align__(16) char smB[2][128 * 64];
  __shared__ float lmax[2][128];

  const int tid = threadIdx.x;
  const int lane = tid & 63;
  const int w = tid >> 6;          // wave 0..3
  const int wm = w >> 1, wn = w & 1;

  // XCD-aware tile coordinates
  const int gid = blockIdx.x;
  const int xcd = gid & 7;
  const int slot = gid >> 3;
  const int rowsPerXcd = (M >> 7) >> 3;          // NRT / 8
  const int rowTile = xcd * rowsPerXcd + slot / NCT;
  const int colTile = slot % NCT;
  const size_t rowBase = (size_t)rowTile * 128;
  const int colBase = colTile * 128;

  floatx4 acc[4][4];
  const floatx4 zero = {0.f, 0.f, 0.f, 0.f};
#pragma unroll
  for (int i = 0; i < 4; ++i)
#pragma unroll
    for (int j = 0; j < 4; ++j) acc[i][j] = zero;

  // staging: wave w stages rows [w*32, w*32+32) of both tiles; per panel: 2 calls
  const int rSub = lane >> 2;            // 0..15
  const int cb16 = (lane & 3) * 16;      // byte within 64B row chunk
  const size_t Kb = (size_t)K * 2;
  const char* gA = (const char*)A + (rowBase + (size_t)(w * 32 + rSub)) * Kb + cb16;
  const char* gB = (const char*)Bw + ((size_t)colBase + (size_t)(w * 32 + rSub)) * Kb + cb16;
  char* lA0 = smA[0] + w * 2048;
  char* lA1 = smA[1] + w * 2048;
  char* lB0 = smB[0] + w * 2048;
  char* lB1 = smB[1] + w * 2048;
  const size_t skip16 = 16 * Kb;

  // fragment addressing
  const int fm = lane & 15, fq = lane >> 4;
  const int fOff = fm * 64 + fq * 16;
  const char* pa0 = smA[0] + wm * 64 * 64 + fOff;
  const char* pa1 = smA[1] + wm * 64 * 64 + fOff;
  const char* pb0 = smB[0] + wn * 64 * 64 + fOff;
  const char* pb1 = smB[1] + wn * 64 * 64 + fOff;

  for (int k0 = 0; k0 < K; k0 += 64) {
    // panel 0: global cols [k0, k0+32); panel 1: [k0+32, k0+64)
    async_cp16(gA, lA0);
    async_cp16(gA + skip16, lA0 + 1024);
    async_cp16(gA + 64, lA1);
    async_cp16(gA + 64 + skip16, lA1 + 1024);
    async_cp16(gB, lB0);
    async_cp16(gB + skip16, lB0 + 1024);
    async_cp16(gB + 64, lB1);
    async_cp16(gB + 64 + skip16, lB1 + 1024);
    gA += 128; gB += 128;                // advance 64 bf16
    __syncthreads();
    bf16x8 af0[4], bg0[4], af1[4], bg1[4];
#pragma unroll
    for (int i = 0; i < 4; ++i) af0[i] = *(const bf16x8*)(pa0 + i * 16 * 64);
#pragma unroll
    for (int j = 0; j < 4; ++j) bg0[j] = *(const bf16x8*)(pb0 + j * 16 * 64);
#pragma unroll
    for (int i = 0; i < 4; ++i)
#pragma unroll
      for (int j = 0; j < 4; ++j)
        acc[i][j] = __builtin_amdgcn_mfma_f32_16x16x32_bf16(af0[i], bg0[j], acc[i][j], 0, 0, 0);
#pragma unroll
    for (int i = 0; i < 4; ++i) af1[i] = *(const bf16x8*)(pa1 + i * 16 * 64);
#pragma unroll
    for (int j = 0; j < 4; ++j) bg1[j] = *(const bf16x8*)(pb1 + j * 16 * 64);
#pragma unroll
    for (int i = 0; i < 4; ++i)
#pragma unroll
      for (int j = 0; j < 4; ++j)
        acc[i][j] = __builtin_amdgcn_mfma_f32_16x16x32_bf16(af1[i], bg1[j], acc[i][j], 0, 0, 0);
    __syncthreads();
  }

  float m4[4] = {-1e30f, -1e30f, -1e30f, -1e30f};

  if (EPI == 0 || EPI == 1 || EPI == 3) {
    unsigned short* O = (unsigned short*)outp;
#pragma unroll
    for (int j = 0; j < 4; ++j) {
      const int col = colBase + wn * 64 + j * 16 + fm;
      const float ex = (EPI == 1) ? extra[(rowBase >> 12) * (size_t)N + col] : extra[col];
#pragma unroll
      for (int i = 0; i < 4; ++i) {
        const size_t row0 = rowBase + wm * 64 + i * 16 + fq * 4;
#pragma unroll
        for (int r = 0; r < 4; ++r) {
          const float v = acc[i][j][r] + ex;
          if (EPI == 3) m4[j] = fmaxf(m4[j], v);
          O[(row0 + r) * (size_t)N + col] = f2bf_bits(v);
        }
      }
    }
  } else {  // EPI == 2: pure column-max
#pragma unroll
    for (int j = 0; j < 4; ++j) {
#pragma unroll
      for (int i = 0; i < 4; ++i)
#pragma unroll
        for (int r = 0; r < 4; ++r) m4[j] = fmaxf(m4[j], acc[i][j][r]);
    }
  }

  if (EPI == 2 || EPI == 3) {
#pragma unroll
    for (int j = 0; j < 4; ++j) {
      m4[j] = fmaxf(m4[j], __shfl_xor(m4[j], 16));
      m4[j] = fmaxf(m4[j], __shfl_xor(m4[j], 32));
    }
    const float sel = (fq == 0) ? m4[0] : (fq == 1) ? m4[1] : (fq == 2) ? m4[2] : m4[3];
    lmax[wm][wn * 64 + fq * 16 + fm] = sel;
    __syncthreads();
    if (tid < 128) {
      const float v = fmaxf(lmax[0][tid], lmax[1][tid]);
      outp2[(size_t)rowTile * N + colBase + tid] = v;
    }
  }
}

// =====================================================================================
// Fused gmax reduce + cvec: per batch b (32 blocks):
//   gm[c]   = max over 32 row-block partials pg[b][s][c]
//   cvec[b][p] = sum_{c<256} w3[p][c] * gm[c]   (fp32 exact)
// =====================================================================================
__global__ __launch_bounds__(256) void gmax_cvec_kernel(
    const float* __restrict__ pg, const float* __restrict__ w3,
    float* __restrict__ cvec) {
  __shared__ float gm[256];
  const int b = blockIdx.x, t = threadIdx.x;
  float m = -1e30f;
  for (int s = 0; s < 32; ++s) m = fmaxf(m, pg[((size_t)b * 32 + s) * 256 + t]);
  gm[t] = m;
  __syncthreads();
#pragma unroll
  for (int half = 0; half < 2; ++half) {
    const int p = half * 256 + t;
    const float* wr = w3 + (size_t)p * 512;
    float s = 0.f;
    for (int c = 0; c < 256; ++c) s += wr[c] * gm[c];
    cvec[b * 512 + p] = s;
  }
}

// =====================================================================================
// K_h: LayerNorm(512) + mask + relu, in place on h46 bf16 [131072 x 512]
// =====================================================================================
__global__ __launch_bounds__(256) void ln2_kernel(
    unsigned short* __restrict__ h46, const int* __restrict__ mask,
    const float* __restrict__ g2, const float* __restrict__ be2) {
  const int lane = threadIdx.x & 63;
  const int wv = threadIdx.x >> 6;
  const size_t p = (size_t)blockIdx.x * 4 + wv;
  unsigned short* row = h46 + p * 512;
  const int c0 = lane * 8;
  union { uint4 v; unsigned short s[8]; } in;
  in.v = *(const uint4*)(row + c0);
  float f[8];
  float s = 0.f;
#pragma unroll
  for (int k = 0; k < 8; ++k) { f[k] = bf2f(in.s[k]); s += f[k]; }
  for (int o = 32; o; o >>= 1) s += __shfl_xor(s, o);
  const float mu = s * (1.f / 512.f);
  float q = 0.f;
#pragma unroll
  for (int k = 0; k < 8; ++k) { const float d = f[k] - mu; q += d * d; }
  for (int o = 32; o; o >>= 1) q += __shfl_xor(q, o);
  const float rs = rsqrtf(q * (1.f / 512.f) + LN_EPS);
  const bool vis = (mask[p] != 0);
  union { uint4 v; unsigned short s[8]; } outv;
#pragma unroll
  for (int k = 0; k < 8; ++k) {
    const float y = vis ? fmaxf((f[k] - mu) * rs * g2[c0 + k] + be2[c0 + k], 0.f) : 0.f;
    outv.s[k] = f2bf_bits(y);
  }
  *(uint4*)(row + c0) = outv.v;
}

// =====================================================================================
// K_j: out[b][f] = max over 32 row-blocks of pmax + b4[f]
// =====================================================================================
__global__ __launch_bounds__(256) void final_kernel(
    const float* __restrict__ pmax, const float* __restrict__ b4,
    float* __restrict__ out) {
  const int idx = blockIdx.x * 256 + threadIdx.x;
  const int b = idx >> 10, f = idx & 1023;
  float m = -1e30f;
  for (int r = 0; r < 32; ++r) m = fmaxf(m, pmax[((size_t)(b * 32 + r)) * 1024 + f]);
  out[idx] = m + b4[f];
}

// =====================================================================================
extern "C" void kernel_launch(void* const* d_in, const int* in_sizes, int n_in,
                              void* d_out, int out_size, void* d_ws, size_t ws_size,
                              hipStream_t stream) {
  const float* points = (const float*)d_in[0];
  const int* mask = (const int*)d_in[1];
  const float* w1 = (const float*)d_in[2];
  const float* g1 = (const float*)d_in[3];
  const float* be1 = (const float*)d_in[4];
  const float* w2 = (const float*)d_in[5];
  const float* b2 = (const float*)d_in[6];
  const float* w3 = (const float*)d_in[7];
  const float* g2 = (const float*)d_in[8];
  const float* be2 = (const float*)d_in[9];
  const float* w4 = (const float*)d_in[10];
  const float* b4 = (const float*)d_in[11];
  float* out = (float*)d_out;
  char* ws = (char*)d_ws;

  // workspace layout (h46 aliases h2: h2 is dead before GEMM3 writes h46)
  const size_t OFF_H46 = 0;                         // 134217728 B (bf16 131072x512)
  const size_t OFF_H2 = 0;                          //  33554432 B (bf16 131072x128)
  const size_t OFF_H3 = 134217728;                  //  67108864 B (bf16 131072x256)
  const size_t OFF_W2B = OFF_H3 + 67108864;         //     65536 B
  const size_t OFF_W3RB = OFF_W2B + 65536;          //    262144 B
  const size_t OFF_W4B = OFF_W3RB + 262144;         //   1048576 B
  const size_t OFF_PG = OFF_W4B + 1048576;          //   1048576 B (pg: 1024x256 f32)
  const size_t OFF_CVEC = OFF_PG + 1048576;         //     65536 B
  const size_t OFF_PMAX = OFF_CVEC + 65536;         //   4194304 B

  unsigned short* h2 = (unsigned short*)(ws + OFF_H2);
  unsigned short* h3 = (unsigned short*)(ws + OFF_H3);
  unsigned short* h46 = (unsigned short*)(ws + OFF_H46);
  unsigned short* w2b = (unsigned short*)(ws + OFF_W2B);
  unsigned short* w3Rb = (unsigned short*)(ws + OFF_W3RB);
  unsigned short* w4b = (unsigned short*)(ws + OFF_W4B);
  float* pg = (float*)(ws + OFF_PG);
  float* cvecp = (float*)(ws + OFF_CVEC);
  float* pmaxp = (float*)(ws + OFF_PMAX);

  // 1. conv1 + LN1 + mask + relu -> h2 ; fused weight fp32->bf16 (blocks >= 32768)
  conv1_ln_kernel<<<32768 + 2688, 256, 0, stream>>>(points, mask, w1, g1, be1, h2,
                                                    w2, w3, w4, w2b, w3Rb, w4b);
  // 2. h3 = h2 @ w2^T + b2, fused per-row-block colmax -> pg
  gemm_bt<3, 2><<<2048, 256, 0, stream>>>(h2, w2b, (void*)h3, pg, b2, 131072, 256, 128);
  // 3. gmax over row-blocks + cvec = w3[:, :256] @ gmax  (fused)
  gmax_cvec_kernel<<<32, 256, 0, stream>>>(pg, w3, cvecp);
  // 4. h4 = h3 @ w3[:,256:]^T + cvec[b]
  gemm_bt<1, 4><<<4096, 256, 0, stream>>>(h3, w3Rb, (void*)h46, nullptr, cvecp, 131072, 512, 256);
  // 5. LN2 + mask + relu in place
  ln2_kernel<<<32768, 256, 0, stream>>>(h46, mask, g2, be2);
  // 6. h7 colmax: fused per-row-block column-max -> pmax (bias deferred)
  gemm_bt<2, 8><<<8192, 256, 0, stream>>>(h46, w4b, nullptr, pmaxp, nullptr, 131072, 1024, 512);
  // 7. out = max over row-blocks + b4
  final_kernel<<<128, 256, 0, stream>>>(pmaxp, b4, out);
}

// Round 6
// 295.622 us; speedup vs baseline: 2.4638x; 1.5768x over previous
//
#include <hip/hip_runtime.h>
#include <stdint.h>

#define LN_EPS 1e-5f

// ---------- bf16 helpers (RNE, bit-level) ----------
static __device__ __forceinline__ unsigned short f2bf_bits(float f) {
  union { float f; unsigned u; } v; v.f = f;
  unsigned r = v.u + 0x7FFFu + ((v.u >> 16) & 1u);
  return (unsigned short)(r >> 16);
}
static __device__ __forceinline__ float bf2f(unsigned short h) {
  union { unsigned u; float f; } v; v.u = ((unsigned)h) << 16;
  return v.f;
}

typedef __bf16 bf16x8 __attribute__((ext_vector_type(8)));
typedef float floatx4 __attribute__((ext_vector_type(4)));

// ---------- async global->LDS, 16B per lane ----------
typedef __attribute__((address_space(1))) unsigned int* gas_ptr;
typedef __attribute__((address_space(3))) unsigned int* las_ptr;
static __device__ __forceinline__ void async_cp16(const void* g, void* l) {
  __builtin_amdgcn_global_load_lds((gas_ptr)g, (las_ptr)l, 16, 0, 0);
}

// =====================================================================================
// perm: per batch, stable partition visible-first. newrow[b*4096+n] = within-batch
// destination row; cnt[b] = #visible. 32 blocks x 256 thr, 16 pts/thr.
// =====================================================================================
__global__ __launch_bounds__(256) void perm_kernel(
    const int* __restrict__ mask, int* __restrict__ newrow, int* __restrict__ cnt) {
  const int b = blockIdx.x, t = threadIdx.x;
  const int base = b * 4096 + t * 16;
  int v[16]; int s = 0;
#pragma unroll
  for (int i = 0; i < 16; ++i) { v[i] = (mask[base + i] != 0); s += v[i]; }
  const int lane = t & 63, wv = t >> 6;
  int scan = s;
  for (int o = 1; o < 64; o <<= 1) { int x = __shfl_up(scan, o); if (lane >= o) scan += x; }
  __shared__ int wsum[4], woff[4], stotal;
  if (lane == 63) wsum[wv] = scan;
  __syncthreads();
  if (t == 0) { int a = 0; for (int k = 0; k < 4; ++k) { woff[k] = a; a += wsum[k]; } stotal = a; cnt[b] = a; }
  __syncthreads();
  const int excl = scan - s + woff[wv];
  const int total = stotal;
  int run = 0;
#pragma unroll
  for (int i = 0; i < 16; ++i) {
    const int pos = t * 16 + i;
    const int visBefore = excl + run;
    newrow[b * 4096 + pos] = v[i] ? visBefore : total + (pos - visBefore);
    run += v[i];
  }
}

// =====================================================================================
// K_b: conv1 (K=3, fp32 exact) + LayerNorm(128) + mask + relu -> h2 bf16, rows
// scattered via newrow (visible-first compaction). blocks >= 32768: fused wconv.
// =====================================================================================
__global__ __launch_bounds__(256) void conv1_ln_kernel(
    const float* __restrict__ points, const int* __restrict__ mask,
    const float* __restrict__ w1, const float* __restrict__ g1,
    const float* __restrict__ be1, unsigned short* __restrict__ h2,
    const int* __restrict__ newrow,
    const float* __restrict__ w2, const float* __restrict__ w3,
    const float* __restrict__ w4, unsigned short* __restrict__ w2b,
    unsigned short* __restrict__ w3Rb, unsigned short* __restrict__ w4b) {
  if (blockIdx.x >= 32768) {   // fused weight conversion: 2688 blocks, 688128 elems
    int idx = (blockIdx.x - 32768) * 256 + threadIdx.x;
    if (idx < 32768) {
      w2b[idx] = f2bf_bits(w2[idx]);
    } else if (idx < 32768 + 131072) {
      int t = idx - 32768;
      int p = t >> 8, k = t & 255;
      w3Rb[t] = f2bf_bits(w3[p * 512 + 256 + k]);   // w3[:, 256:512]
    } else {
      int t = idx - 163840;
      w4b[t] = f2bf_bits(w4[t]);
    }
    return;
  }
  const int lane = threadIdx.x & 63;
  const int wv = threadIdx.x >> 6;
  const size_t p = (size_t)blockIdx.x * 4 + wv;
  const float x0 = points[p * 3 + 0];
  const float x1 = points[p * 3 + 1];
  const float x2 = points[p * 3 + 2];
  const int c0 = lane * 2, c1 = c0 + 1;
  float h00 = w1[c0 * 3] * x0 + w1[c0 * 3 + 1] * x1 + w1[c0 * 3 + 2] * x2;
  float h01 = w1[c1 * 3] * x0 + w1[c1 * 3 + 1] * x1 + w1[c1 * 3 + 2] * x2;
  float s = h00 + h01;
  for (int o = 32; o; o >>= 1) s += __shfl_xor(s, o);
  const float mu = s * (1.f / 128.f);
  const float d0 = h00 - mu, d1 = h01 - mu;
  float q = d0 * d0 + d1 * d1;
  for (int o = 32; o; o >>= 1) q += __shfl_xor(q, o);
  const float rs = rsqrtf(q * (1.f / 128.f) + LN_EPS);
  const bool vis = (mask[p] != 0);
  const float y0 = vis ? fmaxf(d0 * rs * g1[c0] + be1[c0], 0.f) : 0.f;
  const float y1 = vis ? fmaxf(d1 * rs * g1[c1] + be1[c1], 0.f) : 0.f;
  union { unsigned u; unsigned short s2[2]; } pk;
  pk.s2[0] = f2bf_bits(y0);
  pk.s2[1] = f2bf_bits(y1);
  const size_t prow = (p & ~(size_t)4095) + (size_t)newrow[p];
  ((unsigned*)h2)[prow * 64 + lane] = pk.u;
}

// =====================================================================================
// MFMA GEMM: C[M,N] = A[M,K] * Bw[N,K]^T  (bf16 in, fp32 acc), 128x128 tile, BK=64
// (two 32-col panels). XCD-aware swizzle (gid&7 band). Visible-first compaction:
// tiles with rb >= cnt[batch] take a cheap skip path (A rows are all zero there).
// EPI 1: out bf16 = acc + extra[(row>>12)*N + col]; skip -> return (LN2 overwrites)
// EPI 2: outp2[rowTile*N+col] = colmax(acc);         skip -> write 0
// EPI 3: out bf16 = acc + extra[col], colmax -> outp2; skip -> write b2 rows + pg=b2
// =====================================================================================
template <int EPI, int NCT>
__global__ __launch_bounds__(256) void gemm_bt(
    const unsigned short* __restrict__ A, const unsigned short* __restrict__ Bw,
    void* __restrict__ outp, float* __restrict__ outp2,
    const float* __restrict__ extra, const int* __restrict__ cnt,
    int M, int N, int K) {
  __shared__ __align__(16) char smA[2][128 * 64];   // two 8 KB panels (k lo/hi)
  __shared__ __align__(16) char smB[2][128 * 64];
  __shared__ float lmax[2][128];

  const int tid = threadIdx.x;
  const int lane = tid & 63;
  const int w = tid >> 6;          // wave 0..3
  const int wm = w >> 1, wn = w & 1;

  // XCD-aware tile coordinates
  const int gid = blockIdx.x;
  const int xcd = gid & 7;
  const int slot = gid >> 3;
  const int rowsPerXcd = (M >> 7) >> 3;          // NRT / 8
  const int rowTile = xcd * rowsPerXcd + slot / NCT;
  const int colTile = slot % NCT;
  const size_t rowBase = (size_t)rowTile * 128;
  const int colBase = colTile * 128;

  // sparsity skip: rows [rowBase, rowBase+128) all zero-A when rb >= cnt[batch]
  const int cntb = cnt[rowBase >> 12];
  const int rb = (int)(rowBase & 4095);
  if (rb >= cntb) {
    if (EPI == 1) return;                              // LN2 writes these rows
    if (EPI == 2) {                                    // masked-row contribution = 0
      if (tid < 128) outp2[(size_t)rowTile * N + colBase + tid] = 0.f;
      return;
    }
    if (EPI == 3) {                                    // h3 rows = b2 exactly
      unsigned short* O = (unsigned short*)outp;
      const int col = colBase + (tid & 127);
      const unsigned short bv = f2bf_bits(extra[col]);
      const int r0 = (tid >> 7) * 64;
      for (int r = r0; r < r0 + 64; ++r) O[(rowBase + r) * (size_t)N + col] = bv;
      if (tid < 128) outp2[(size_t)rowTile * N + colBase + tid] = extra[colBase + tid];
      return;
    }
  }

  floatx4 acc[4][4];
  const floatx4 zero = {0.f, 0.f, 0.f, 0.f};
#pragma unroll
  for (int i = 0; i < 4; ++i)
#pragma unroll
    for (int j = 0; j < 4; ++j) acc[i][j] = zero;

  // staging: wave w stages rows [w*32, w*32+32) of both tiles; per panel: 2 calls
  const int rSub = lane >> 2;            // 0..15
  const int cb16 = (lane & 3) * 16;      // byte within 64B row chunk
  const size_t Kb = (size_t)K * 2;
  const char* gA = (const char*)A + (rowBase + (size_t)(w * 32 + rSub)) * Kb + cb16;
  const char* gB = (const char*)Bw + ((size_t)colBase + (size_t)(w * 32 + rSub)) * Kb + cb16;
  char* lA0 = smA[0] + w * 2048;
  char* lA1 = smA[1] + w * 2048;
  char* lB0 = smB[0] + w * 2048;
  char* lB1 = smB[1] + w * 2048;
  const size_t skip16 = 16 * Kb;

  // fragment addressing
  const int fm = lane & 15, fq = lane >> 4;
  const int fOff = fm * 64 + fq * 16;
  const char* pa0 = smA[0] + wm * 64 * 64 + fOff;
  const char* pa1 = smA[1] + wm * 64 * 64 + fOff;
  const char* pb0 = smB[0] + wn * 64 * 64 + fOff;
  const char* pb1 = smB[1] + wn * 64 * 64 + fOff;

  for (int k0 = 0; k0 < K; k0 += 64) {
    async_cp16(gA, lA0);
    async_cp16(gA + skip16, lA0 + 1024);
    async_cp16(gA + 64, lA1);
    async_cp16(gA + 64 + skip16, lA1 + 1024);
    async_cp16(gB, lB0);
    async_cp16(gB + skip16, lB0 + 1024);
    async_cp16(gB + 64, lB1);
    async_cp16(gB + 64 + skip16, lB1 + 1024);
    gA += 128; gB += 128;                // advance 64 bf16
    __syncthreads();
    bf16x8 af0[4], bg0[4], af1[4], bg1[4];
#pragma unroll
    for (int i = 0; i < 4; ++i) af0[i] = *(const bf16x8*)(pa0 + i * 16 * 64);
#pragma unroll
    for (int j = 0; j < 4; ++j) bg0[j] = *(const bf16x8*)(pb0 + j * 16 * 64);
#pragma unroll
    for (int i = 0; i < 4; ++i)
#pragma unroll
      for (int j = 0; j < 4; ++j)
        acc[i][j] = __builtin_amdgcn_mfma_f32_16x16x32_bf16(af0[i], bg0[j], acc[i][j], 0, 0, 0);
#pragma unroll
    for (int i = 0; i < 4; ++i) af1[i] = *(const bf16x8*)(pa1 + i * 16 * 64);
#pragma unroll
    for (int j = 0; j < 4; ++j) bg1[j] = *(const bf16x8*)(pb1 + j * 16 * 64);
#pragma unroll
    for (int i = 0; i < 4; ++i)
#pragma unroll
      for (int j = 0; j < 4; ++j)
        acc[i][j] = __builtin_amdgcn_mfma_f32_16x16x32_bf16(af1[i], bg1[j], acc[i][j], 0, 0, 0);
    __syncthreads();
  }

  float m4[4] = {-1e30f, -1e30f, -1e30f, -1e30f};

  if (EPI == 1 || EPI == 3) {
    unsigned short* O = (unsigned short*)outp;
#pragma unroll
    for (int j = 0; j < 4; ++j) {
      const int col = colBase + wn * 64 + j * 16 + fm;
      const float ex = (EPI == 1) ? extra[(rowBase >> 12) * (size_t)N + col] : extra[col];
#pragma unroll
      for (int i = 0; i < 4; ++i) {
        const size_t row0 = rowBase + wm * 64 + i * 16 + fq * 4;
#pragma unroll
        for (int r = 0; r < 4; ++r) {
          const float v = acc[i][j][r] + ex;
          if (EPI == 3) m4[j] = fmaxf(m4[j], v);
          O[(row0 + r) * (size_t)N + col] = f2bf_bits(v);
        }
      }
    }
  } else {  // EPI == 2: pure column-max
#pragma unroll
    for (int j = 0; j < 4; ++j) {
#pragma unroll
      for (int i = 0; i < 4; ++i)
#pragma unroll
        for (int r = 0; r < 4; ++r) m4[j] = fmaxf(m4[j], acc[i][j][r]);
    }
  }

  if (EPI == 2 || EPI == 3) {
#pragma unroll
    for (int j = 0; j < 4; ++j) {
      m4[j] = fmaxf(m4[j], __shfl_xor(m4[j], 16));
      m4[j] = fmaxf(m4[j], __shfl_xor(m4[j], 32));
    }
    const float sel = (fq == 0) ? m4[0] : (fq == 1) ? m4[1] : (fq == 2) ? m4[2] : m4[3];
    lmax[wm][wn * 64 + fq * 16 + fm] = sel;
    __syncthreads();
    if (tid < 128) {
      const float v = fmaxf(lmax[0][tid], lmax[1][tid]);
      outp2[(size_t)rowTile * N + colBase + tid] = v;
    }
  }
}

// =====================================================================================
// Fused gmax reduce + cvec (per batch): gm = max over 32 pg partials; cvec = w3L @ gm
// =====================================================================================
__global__ __launch_bounds__(256) void gmax_cvec_kernel(
    const float* __restrict__ pg, const float* __restrict__ w3,
    float* __restrict__ cvec) {
  __shared__ float gm[256];
  const int b = blockIdx.x, t = threadIdx.x;
  float m = -1e30f;
  for (int s = 0; s < 32; ++s) m = fmaxf(m, pg[((size_t)b * 32 + s) * 256 + t]);
  gm[t] = m;
  __syncthreads();
#pragma unroll
  for (int half = 0; half < 2; ++half) {
    const int p = half * 256 + t;
    const float* wr = w3 + (size_t)p * 512;
    float s = 0.f;
    for (int c = 0; c < 256; ++c) s += wr[c] * gm[c];
    cvec[b * 512 + p] = s;
  }
}

// =====================================================================================
// K_h: LayerNorm(512) + relu in place on h46 (compacted: rows < cnt[b] are visible;
// rows >= cnt get zeros without reading).
// =====================================================================================
__global__ __launch_bounds__(256) void ln2_kernel(
    unsigned short* __restrict__ h46, const int* __restrict__ cnt,
    const float* __restrict__ g2, const float* __restrict__ be2) {
  const int lane = threadIdx.x & 63;
  const int wv = threadIdx.x >> 6;
  const size_t p = (size_t)blockIdx.x * 4 + wv;
  unsigned short* row = h46 + p * 512;
  const int c0 = lane * 8;
  if ((int)(p & 4095) >= cnt[p >> 12]) {     // masked (or pad) row -> zeros
    const uint4 z = {0, 0, 0, 0};
    *(uint4*)(row + c0) = z;
    return;
  }
  union { uint4 v; unsigned short s[8]; } in;
  in.v = *(const uint4*)(row + c0);
  float f[8];
  float s = 0.f;
#pragma unroll
  for (int k = 0; k < 8; ++k) { f[k] = bf2f(in.s[k]); s += f[k]; }
  for (int o = 32; o; o >>= 1) s += __shfl_xor(s, o);
  const float mu = s * (1.f / 512.f);
  float q = 0.f;
#pragma unroll
  for (int k = 0; k < 8; ++k) { const float d = f[k] - mu; q += d * d; }
  for (int o = 32; o; o >>= 1) q += __shfl_xor(q, o);
  const float rs = rsqrtf(q * (1.f / 512.f) + LN_EPS);
  union { uint4 v; unsigned short s[8]; } outv;
#pragma unroll
  for (int k = 0; k < 8; ++k) {
    const float y = fmaxf((f[k] - mu) * rs * g2[c0 + k] + be2[c0 + k], 0.f);
    outv.s[k] = f2bf_bits(y);
  }
  *(uint4*)(row + c0) = outv.v;
}

// =====================================================================================
// K_j: out[b][f] = max over 32 row-blocks of pmax + b4[f]
// =====================================================================================
__global__ __launch_bounds__(256) void final_kernel(
    const float* __restrict__ pmax, const float* __restrict__ b4,
    float* __restrict__ out) {
  const int idx = blockIdx.x * 256 + threadIdx.x;
  const int b = idx >> 10, f = idx & 1023;
  float m = -1e30f;
  for (int r = 0; r < 32; ++r) m = fmaxf(m, pmax[((size_t)(b * 32 + r)) * 1024 + f]);
  out[idx] = m + b4[f];
}

// =====================================================================================
extern "C" void kernel_launch(void* const* d_in, const int* in_sizes, int n_in,
                              void* d_out, int out_size, void* d_ws, size_t ws_size,
                              hipStream_t stream) {
  const float* points = (const float*)d_in[0];
  const int* mask = (const int*)d_in[1];
  const float* w1 = (const float*)d_in[2];
  const float* g1 = (const float*)d_in[3];
  const float* be1 = (const float*)d_in[4];
  const float* w2 = (const float*)d_in[5];
  const float* b2 = (const float*)d_in[6];
  const float* w3 = (const float*)d_in[7];
  const float* g2 = (const float*)d_in[8];
  const float* be2 = (const float*)d_in[9];
  const float* w4 = (const float*)d_in[10];
  const float* b4 = (const float*)d_in[11];
  float* out = (float*)d_out;
  char* ws = (char*)d_ws;

  // workspace layout (h46 aliases h2: h2 is dead before GEMM3 writes h46)
  const size_t OFF_H46 = 0;                         // 134217728 B (bf16 131072x512)
  const size_t OFF_H2 = 0;                          //  33554432 B (bf16 131072x128)
  const size_t OFF_H3 = 134217728;                  //  67108864 B (bf16 131072x256)
  const size_t OFF_W2B = OFF_H3 + 67108864;         //     65536 B
  const size_t OFF_W3RB = OFF_W2B + 65536;          //    262144 B
  const size_t OFF_W4B = OFF_W3RB + 262144;         //   1048576 B
  const size_t OFF_PG = OFF_W4B + 1048576;          //   1048576 B (pg: 1024x256 f32)
  const size_t OFF_CVEC = OFF_PG + 1048576;         //     65536 B
  const size_t OFF_PMAX = OFF_CVEC + 65536;         //   4194304 B
  const size_t OFF_CNT = OFF_PMAX + 4194304;        //      4096 B (32 ints, padded)
  const size_t OFF_NEWROW = OFF_CNT + 4096;         //    524288 B

  unsigned short* h2 = (unsigned short*)(ws + OFF_H2);
  unsigned short* h3 = (unsigned short*)(ws + OFF_H3);
  unsigned short* h46 = (unsigned short*)(ws + OFF_H46);
  unsigned short* w2b = (unsigned short*)(ws + OFF_W2B);
  unsigned short* w3Rb = (unsigned short*)(ws + OFF_W3RB);
  unsigned short* w4b = (unsigned short*)(ws + OFF_W4B);
  float* pg = (float*)(ws + OFF_PG);
  float* cvecp = (float*)(ws + OFF_CVEC);
  float* pmaxp = (float*)(ws + OFF_PMAX);
  int* cntp = (int*)(ws + OFF_CNT);
  int* newrow = (int*)(ws + OFF_NEWROW);

  // 0. visible-first compaction map per batch
  perm_kernel<<<32, 256, 0, stream>>>(mask, newrow, cntp);
  // 1. conv1 + LN1 + mask + relu -> h2 (compacted rows); fused weight fp32->bf16
  conv1_ln_kernel<<<32768 + 2688, 256, 0, stream>>>(points, mask, w1, g1, be1, h2,
                                                    newrow, w2, w3, w4, w2b, w3Rb, w4b);
  // 2. h3 = h2 @ w2^T + b2, fused per-row-block colmax -> pg (skip tiles -> b2)
  gemm_bt<3, 2><<<2048, 256, 0, stream>>>(h2, w2b, (void*)h3, pg, b2, cntp, 131072, 256, 128);
  // 3. gmax over row-blocks + cvec = w3[:, :256] @ gmax  (fused)
  gmax_cvec_kernel<<<32, 256, 0, stream>>>(pg, w3, cvecp);
  // 4. h4 = h3 @ w3[:,256:]^T + cvec[b]  (skip tiles past cnt: LN2 fills them)
  gemm_bt<1, 4><<<4096, 256, 0, stream>>>(h3, w3Rb, (void*)h46, nullptr, cvecp, cntp, 131072, 512, 256);
  // 5. LN2 + relu in place; rows >= cnt[b] -> zeros (no read)
  ln2_kernel<<<32768, 256, 0, stream>>>(h46, cntp, g2, be2);
  // 6. h7 colmax -> pmax (skip tiles write 0 = masked-row contribution)
  gemm_bt<2, 8><<<8192, 256, 0, stream>>>(h46, w4b, nullptr, pmaxp, nullptr, cntp, 131072, 1024, 512);
  // 7. out = max over row-blocks + b4
  final_kernel<<<128, 256, 0, stream>>>(pmaxp, b4, out);
}

// Round 7
// 287.300 us; speedup vs baseline: 2.5351x; 1.0290x over previous
//
#include <hip/hip_runtime.h>
#include <stdint.h>

#define LN_EPS 1e-5f

// ---------- bf16 helpers (RNE, bit-level) ----------
static __device__ __forceinline__ unsigned short f2bf_bits(float f) {
  union { float f; unsigned u; } v; v.f = f;
  unsigned r = v.u + 0x7FFFu + ((v.u >> 16) & 1u);
  return (unsigned short)(r >> 16);
}
static __device__ __forceinline__ float bf2f(unsigned short h) {
  union { unsigned u; float f; } v; v.u = ((unsigned)h) << 16;
  return v.f;
}

typedef __bf16 bf16x8 __attribute__((ext_vector_type(8)));
typedef float floatx4 __attribute__((ext_vector_type(4)));

// ---------- async global->LDS, 16B per lane ----------
typedef __attribute__((address_space(1))) unsigned int* gas_ptr;
typedef __attribute__((address_space(3))) unsigned int* las_ptr;
static __device__ __forceinline__ void async_cp16(const void* g, void* l) {
  __builtin_amdgcn_global_load_lds((gas_ptr)g, (las_ptr)l, 16, 0, 0);
}

// =====================================================================================
// perm: per batch, stable partition visible-first. newrow[b*4096+n] = within-batch
// destination row; cnt[b] = #visible. 32 blocks x 256 thr, 16 pts/thr.
// =====================================================================================
__global__ __launch_bounds__(256) void perm_kernel(
    const int* __restrict__ mask, int* __restrict__ newrow, int* __restrict__ cnt) {
  const int b = blockIdx.x, t = threadIdx.x;
  const int base = b * 4096 + t * 16;
  int v[16]; int s = 0;
#pragma unroll
  for (int i = 0; i < 16; ++i) { v[i] = (mask[base + i] != 0); s += v[i]; }
  const int lane = t & 63, wv = t >> 6;
  int scan = s;
  for (int o = 1; o < 64; o <<= 1) { int x = __shfl_up(scan, o); if (lane >= o) scan += x; }
  __shared__ int wsum[4], woff[4], stotal;
  if (lane == 63) wsum[wv] = scan;
  __syncthreads();
  if (t == 0) { int a = 0; for (int k = 0; k < 4; ++k) { woff[k] = a; a += wsum[k]; } stotal = a; cnt[b] = a; }
  __syncthreads();
  const int excl = scan - s + woff[wv];
  const int total = stotal;
  int run = 0;
#pragma unroll
  for (int i = 0; i < 16; ++i) {
    const int pos = t * 16 + i;
    const int visBefore = excl + run;
    newrow[b * 4096 + pos] = v[i] ? visBefore : total + (pos - visBefore);
    run += v[i];
  }
}

// =====================================================================================
// K_b: conv1 (K=3, fp32 exact) + LayerNorm(128) + mask + relu -> h2 bf16, rows
// scattered via newrow (visible-first). Rows >= ceil128(cnt) are never read by
// GEMM2 (skip tiles) -> not written. blocks >= 32768: fused wconv.
// =====================================================================================
__global__ __launch_bounds__(256) void conv1_ln_kernel(
    const float* __restrict__ points, const int* __restrict__ mask,
    const float* __restrict__ w1, const float* __restrict__ g1,
    const float* __restrict__ be1, unsigned short* __restrict__ h2,
    const int* __restrict__ newrow, const int* __restrict__ cnt,
    const float* __restrict__ w2, const float* __restrict__ w3,
    const float* __restrict__ w4, unsigned short* __restrict__ w2b,
    unsigned short* __restrict__ w3Rb, unsigned short* __restrict__ w4b) {
  if (blockIdx.x >= 32768) {   // fused weight conversion: 2688 blocks, 688128 elems
    int idx = (blockIdx.x - 32768) * 256 + threadIdx.x;
    if (idx < 32768) {
      w2b[idx] = f2bf_bits(w2[idx]);
    } else if (idx < 32768 + 131072) {
      int t = idx - 32768;
      int p = t >> 8, k = t & 255;
      w3Rb[t] = f2bf_bits(w3[p * 512 + 256 + k]);   // w3[:, 256:512]
    } else {
      int t = idx - 163840;
      w4b[t] = f2bf_bits(w4[t]);
    }
    return;
  }
  const int lane = threadIdx.x & 63;
  const int wv = threadIdx.x >> 6;
  const size_t p = (size_t)blockIdx.x * 4 + wv;
  const int dest = newrow[p];
  const int ceilv = (cnt[p >> 12] + 127) & ~127;
  if (dest >= ceilv) return;                 // row never read downstream
  const float x0 = points[p * 3 + 0];
  const float x1 = points[p * 3 + 1];
  const float x2 = points[p * 3 + 2];
  const int c0 = lane * 2, c1 = c0 + 1;
  float h00 = w1[c0 * 3] * x0 + w1[c0 * 3 + 1] * x1 + w1[c0 * 3 + 2] * x2;
  float h01 = w1[c1 * 3] * x0 + w1[c1 * 3 + 1] * x1 + w1[c1 * 3 + 2] * x2;
  float s = h00 + h01;
  for (int o = 32; o; o >>= 1) s += __shfl_xor(s, o);
  const float mu = s * (1.f / 128.f);
  const float d0 = h00 - mu, d1 = h01 - mu;
  float q = d0 * d0 + d1 * d1;
  for (int o = 32; o; o >>= 1) q += __shfl_xor(q, o);
  const float rs = rsqrtf(q * (1.f / 128.f) + LN_EPS);
  const bool vis = (mask[p] != 0);
  const float y0 = vis ? fmaxf(d0 * rs * g1[c0] + be1[c0], 0.f) : 0.f;
  const float y1 = vis ? fmaxf(d1 * rs * g1[c1] + be1[c1], 0.f) : 0.f;
  union { unsigned u; unsigned short s2[2]; } pk;
  pk.s2[0] = f2bf_bits(y0);
  pk.s2[1] = f2bf_bits(y1);
  const size_t prow = (p & ~(size_t)4095) + (size_t)dest;
  ((unsigned*)h2)[prow * 64 + lane] = pk.u;
}

// =====================================================================================
// MFMA GEMM: C[M,N] = A[M,K] * Bw[N,K]^T  (bf16 in, fp32 acc), 128x128 tile, BK=64
// (two 32-col panels). XCD-aware swizzle (gid&7 band). Visible-first compaction:
// tiles with rb >= cnt[batch] take a cheap skip path (A rows are all zero there).
// EPI 1: out bf16 = acc + extra[(row>>12)*N + col]; skip -> return (no readers)
// EPI 2: outp2[rowTile*N+col] = colmax(acc);         skip -> write 0
// EPI 3: out bf16 = acc + extra[col], colmax -> outp2; skip -> pg=b2 only
//        (skip-tile h3 rows have no readers: GEMM3 skips them too)
// =====================================================================================
template <int EPI, int NCT>
__global__ __launch_bounds__(256) void gemm_bt(
    const unsigned short* __restrict__ A, const unsigned short* __restrict__ Bw,
    void* __restrict__ outp, float* __restrict__ outp2,
    const float* __restrict__ extra, const int* __restrict__ cnt,
    int M, int N, int K) {
  __shared__ __align__(16) char smA[2][128 * 64];   // two 8 KB panels (k lo/hi)
  __shared__ __align__(16) char smB[2][128 * 64];
  __shared__ float lmax[2][128];

  const int tid = threadIdx.x;
  const int lane = tid & 63;
  const int w = tid >> 6;          // wave 0..3
  const int wm = w >> 1, wn = w & 1;

  // XCD-aware tile coordinates
  const int gid = blockIdx.x;
  const int xcd = gid & 7;
  const int slot = gid >> 3;
  const int rowsPerXcd = (M >> 7) >> 3;          // NRT / 8
  const int rowTile = xcd * rowsPerXcd + slot / NCT;
  const int colTile = slot % NCT;
  const size_t rowBase = (size_t)rowTile * 128;
  const int colBase = colTile * 128;

  // sparsity skip: rows [rowBase, rowBase+128) all zero-A when rb >= cnt[batch]
  const int cntb = cnt[rowBase >> 12];
  const int rb = (int)(rowBase & 4095);
  if (rb >= cntb) {
    if (EPI == 1) return;                              // LN2/nobody reads these rows
    if (EPI == 2) {                                    // masked-row contribution = 0
      if (tid < 128) outp2[(size_t)rowTile * N + colBase + tid] = 0.f;
      return;
    }
    if (EPI == 3) {                                    // gmax contribution = b2
      if (tid < 128) outp2[(size_t)rowTile * N + colBase + tid] = extra[colBase + tid];
      return;
    }
  }

  floatx4 acc[4][4];
  const floatx4 zero = {0.f, 0.f, 0.f, 0.f};
#pragma unroll
  for (int i = 0; i < 4; ++i)
#pragma unroll
    for (int j = 0; j < 4; ++j) acc[i][j] = zero;

  // staging: wave w stages rows [w*32, w*32+32) of both tiles; per panel: 2 calls
  const int rSub = lane >> 2;            // 0..15
  const int cb16 = (lane & 3) * 16;      // byte within 64B row chunk
  const size_t Kb = (size_t)K * 2;
  const char* gA = (const char*)A + (rowBase + (size_t)(w * 32 + rSub)) * Kb + cb16;
  const char* gB = (const char*)Bw + ((size_t)colBase + (size_t)(w * 32 + rSub)) * Kb + cb16;
  char* lA0 = smA[0] + w * 2048;
  char* lA1 = smA[1] + w * 2048;
  char* lB0 = smB[0] + w * 2048;
  char* lB1 = smB[1] + w * 2048;
  const size_t skip16 = 16 * Kb;

  // fragment addressing
  const int fm = lane & 15, fq = lane >> 4;
  const int fOff = fm * 64 + fq * 16;
  const char* pa0 = smA[0] + wm * 64 * 64 + fOff;
  const char* pa1 = smA[1] + wm * 64 * 64 + fOff;
  const char* pb0 = smB[0] + wn * 64 * 64 + fOff;
  const char* pb1 = smB[1] + wn * 64 * 64 + fOff;

  for (int k0 = 0; k0 < K; k0 += 64) {
    async_cp16(gA, lA0);
    async_cp16(gA + skip16, lA0 + 1024);
    async_cp16(gA + 64, lA1);
    async_cp16(gA + 64 + skip16, lA1 + 1024);
    async_cp16(gB, lB0);
    async_cp16(gB + skip16, lB0 + 1024);
    async_cp16(gB + 64, lB1);
    async_cp16(gB + 64 + skip16, lB1 + 1024);
    gA += 128; gB += 128;                // advance 64 bf16
    __syncthreads();
    bf16x8 af0[4], bg0[4], af1[4], bg1[4];
#pragma unroll
    for (int i = 0; i < 4; ++i) af0[i] = *(const bf16x8*)(pa0 + i * 16 * 64);
#pragma unroll
    for (int j = 0; j < 4; ++j) bg0[j] = *(const bf16x8*)(pb0 + j * 16 * 64);
#pragma unroll
    for (int i = 0; i < 4; ++i)
#pragma unroll
      for (int j = 0; j < 4; ++j)
        acc[i][j] = __builtin_amdgcn_mfma_f32_16x16x32_bf16(af0[i], bg0[j], acc[i][j], 0, 0, 0);
#pragma unroll
    for (int i = 0; i < 4; ++i) af1[i] = *(const bf16x8*)(pa1 + i * 16 * 64);
#pragma unroll
    for (int j = 0; j < 4; ++j) bg1[j] = *(const bf16x8*)(pb1 + j * 16 * 64);
#pragma unroll
    for (int i = 0; i < 4; ++i)
#pragma unroll
      for (int j = 0; j < 4; ++j)
        acc[i][j] = __builtin_amdgcn_mfma_f32_16x16x32_bf16(af1[i], bg1[j], acc[i][j], 0, 0, 0);
    __syncthreads();
  }

  float m4[4] = {-1e30f, -1e30f, -1e30f, -1e30f};

  if (EPI == 1 || EPI == 3) {
    unsigned short* O = (unsigned short*)outp;
#pragma unroll
    for (int j = 0; j < 4; ++j) {
      const int col = colBase + wn * 64 + j * 16 + fm;
      const float ex = (EPI == 1) ? extra[(rowBase >> 12) * (size_t)N + col] : extra[col];
#pragma unroll
      for (int i = 0; i < 4; ++i) {
        const size_t row0 = rowBase + wm * 64 + i * 16 + fq * 4;
#pragma unroll
        for (int r = 0; r < 4; ++r) {
          const float v = acc[i][j][r] + ex;
          if (EPI == 3) m4[j] = fmaxf(m4[j], v);
          O[(row0 + r) * (size_t)N + col] = f2bf_bits(v);
        }
      }
    }
  } else {  // EPI == 2: pure column-max
#pragma unroll
    for (int j = 0; j < 4; ++j) {
#pragma unroll
      for (int i = 0; i < 4; ++i)
#pragma unroll
        for (int r = 0; r < 4; ++r) m4[j] = fmaxf(m4[j], acc[i][j][r]);
    }
  }

  if (EPI == 2 || EPI == 3) {
#pragma unroll
    for (int j = 0; j < 4; ++j) {
      m4[j] = fmaxf(m4[j], __shfl_xor(m4[j], 16));
      m4[j] = fmaxf(m4[j], __shfl_xor(m4[j], 32));
    }
    const float sel = (fq == 0) ? m4[0] : (fq == 1) ? m4[1] : (fq == 2) ? m4[2] : m4[3];
    lmax[wm][wn * 64 + fq * 16 + fm] = sel;
    __syncthreads();
    if (tid < 128) {
      const float v = fmaxf(lmax[0][tid], lmax[1][tid]);
      outp2[(size_t)rowTile * N + colBase + tid] = v;
    }
  }
}

// =====================================================================================
// Fused gmax reduce + cvec (per batch): gm = max over 32 pg partials; cvec = w3L @ gm
// =====================================================================================
__global__ __launch_bounds__(256) void gmax_cvec_kernel(
    const float* __restrict__ pg, const float* __restrict__ w3,
    float* __restrict__ cvec) {
  __shared__ float gm[256];
  const int b = blockIdx.x, t = threadIdx.x;
  float m = -1e30f;
  for (int s = 0; s < 32; ++s) m = fmaxf(m, pg[((size_t)b * 32 + s) * 256 + t]);
  gm[t] = m;
  __syncthreads();
#pragma unroll
  for (int half = 0; half < 2; ++half) {
    const int p = half * 256 + t;
    const float* wr = w3 + (size_t)p * 512;
    float s = 0.f;
    for (int c = 0; c < 256; ++c) s += wr[c] * gm[c];
    cvec[b * 512 + p] = s;
  }
}

// =====================================================================================
// K_h: LayerNorm(512) + relu in place on h46 (compacted). rows < cnt: LN+relu;
// rows in [cnt, ceil128(cnt)): zero (read by GEMM4 straddle tile);
// rows >= ceil128: untouched (no readers).
// =====================================================================================
__global__ __launch_bounds__(256) void ln2_kernel(
    unsigned short* __restrict__ h46, const int* __restrict__ cnt,
    const float* __restrict__ g2, const float* __restrict__ be2) {
  const int lane = threadIdx.x & 63;
  const int wv = threadIdx.x >> 6;
  const size_t p = (size_t)blockIdx.x * 4 + wv;
  const int cb = cnt[p >> 12];
  const int pin = (int)(p & 4095);
  const int ceilv = (cb + 127) & ~127;
  if (pin >= ceilv) return;
  unsigned short* row = h46 + p * 512;
  const int c0 = lane * 8;
  if (pin >= cb) {                            // straddle zero-fill
    const uint4 z = {0, 0, 0, 0};
    *(uint4*)(row + c0) = z;
    return;
  }
  union { uint4 v; unsigned short s[8]; } in;
  in.v = *(const uint4*)(row + c0);
  float f[8];
  float s = 0.f;
#pragma unroll
  for (int k = 0; k < 8; ++k) { f[k] = bf2f(in.s[k]); s += f[k]; }
  for (int o = 32; o; o >>= 1) s += __shfl_xor(s, o);
  const float mu = s * (1.f / 512.f);
  float q = 0.f;
#pragma unroll
  for (int k = 0; k < 8; ++k) { const float d = f[k] - mu; q += d * d; }
  for (int o = 32; o; o >>= 1) q += __shfl_xor(q, o);
  const float rs = rsqrtf(q * (1.f / 512.f) + LN_EPS);
  union { uint4 v; unsigned short s[8]; } outv;
#pragma unroll
  for (int k = 0; k < 8; ++k) {
    const float y = fmaxf((f[k] - mu) * rs * g2[c0 + k] + be2[c0 + k], 0.f);
    outv.s[k] = f2bf_bits(y);
  }
  *(uint4*)(row + c0) = outv.v;
}

// =====================================================================================
// K_j: out[b][f] = max over 32 row-blocks of pmax + b4[f]
// =====================================================================================
__global__ __launch_bounds__(256) void final_kernel(
    const float* __restrict__ pmax, const float* __restrict__ b4,
    float* __restrict__ out) {
  const int idx = blockIdx.x * 256 + threadIdx.x;
  const int b = idx >> 10, f = idx & 1023;
  float m = -1e30f;
  for (int r = 0; r < 32; ++r) m = fmaxf(m, pmax[((size_t)(b * 32 + r)) * 1024 + f]);
  out[idx] = m + b4[f];
}

// =====================================================================================
extern "C" void kernel_launch(void* const* d_in, const int* in_sizes, int n_in,
                              void* d_out, int out_size, void* d_ws, size_t ws_size,
                              hipStream_t stream) {
  const float* points = (const float*)d_in[0];
  const int* mask = (const int*)d_in[1];
  const float* w1 = (const float*)d_in[2];
  const float* g1 = (const float*)d_in[3];
  const float* be1 = (const float*)d_in[4];
  const float* w2 = (const float*)d_in[5];
  const float* b2 = (const float*)d_in[6];
  const float* w3 = (const float*)d_in[7];
  const float* g2 = (const float*)d_in[8];
  const float* be2 = (const float*)d_in[9];
  const float* w4 = (const float*)d_in[10];
  const float* b4 = (const float*)d_in[11];
  float* out = (float*)d_out;
  char* ws = (char*)d_ws;

  // workspace layout (h46 aliases h2: h2 is dead before GEMM3 writes h46)
  const size_t OFF_H46 = 0;                         // 134217728 B (bf16 131072x512)
  const size_t OFF_H2 = 0;                          //  33554432 B (bf16 131072x128)
  const size_t OFF_H3 = 134217728;                  //  67108864 B (bf16 131072x256)
  const size_t OFF_W2B = OFF_H3 + 67108864;         //     65536 B
  const size_t OFF_W3RB = OFF_W2B + 65536;          //    262144 B
  const size_t OFF_W4B = OFF_W3RB + 262144;         //   1048576 B
  const size_t OFF_PG = OFF_W4B + 1048576;          //   1048576 B (pg: 1024x256 f32)
  const size_t OFF_CVEC = OFF_PG + 1048576;         //     65536 B
  const size_t OFF_PMAX = OFF_CVEC + 65536;         //   4194304 B
  const size_t OFF_CNT = OFF_PMAX + 4194304;        //      4096 B (32 ints, padded)
  const size_t OFF_NEWROW = OFF_CNT + 4096;         //    524288 B

  unsigned short* h2 = (unsigned short*)(ws + OFF_H2);
  unsigned short* h3 = (unsigned short*)(ws + OFF_H3);
  unsigned short* h46 = (unsigned short*)(ws + OFF_H46);
  unsigned short* w2b = (unsigned short*)(ws + OFF_W2B);
  unsigned short* w3Rb = (unsigned short*)(ws + OFF_W3RB);
  unsigned short* w4b = (unsigned short*)(ws + OFF_W4B);
  float* pg = (float*)(ws + OFF_PG);
  float* cvecp = (float*)(ws + OFF_CVEC);
  float* pmaxp = (float*)(ws + OFF_PMAX);
  int* cntp = (int*)(ws + OFF_CNT);
  int* newrow = (int*)(ws + OFF_NEWROW);

  // 0. visible-first compaction map per batch
  perm_kernel<<<32, 256, 0, stream>>>(mask, newrow, cntp);
  // 1. conv1 + LN1 + mask + relu -> h2 (compacted rows); fused weight fp32->bf16
  conv1_ln_kernel<<<32768 + 2688, 256, 0, stream>>>(points, mask, w1, g1, be1, h2,
                                                    newrow, cntp, w2, w3, w4, w2b, w3Rb, w4b);
  // 2. h3 = h2 @ w2^T + b2, fused per-row-block colmax -> pg (skip tiles: pg=b2 only)
  gemm_bt<3, 2><<<2048, 256, 0, stream>>>(h2, w2b, (void*)h3, pg, b2, cntp, 131072, 256, 128);
  // 3. gmax over row-blocks + cvec = w3[:, :256] @ gmax  (fused)
  gmax_cvec_kernel<<<32, 256, 0, stream>>>(pg, w3, cvecp);
  // 4. h4 = h3 @ w3[:,256:]^T + cvec[b]  (skip tiles return)
  gemm_bt<1, 4><<<4096, 256, 0, stream>>>(h3, w3Rb, (void*)h46, nullptr, cvecp, cntp, 131072, 512, 256);
  // 5. LN2 + relu in place; zero only straddle rows [cnt, ceil128)
  ln2_kernel<<<32768, 256, 0, stream>>>(h46, cntp, g2, be2);
  // 6. h7 colmax -> pmax (skip tiles write 0 = masked-row contribution)
  gemm_bt<2, 8><<<8192, 256, 0, stream>>>(h46, w4b, nullptr, pmaxp, nullptr, cntp, 131072, 1024, 512);
  // 7. out = max over row-blocks + b4
  final_kernel<<<128, 256, 0, stream>>>(pmaxp, b4, out);
}